// Round 10
// baseline (182.440 us; speedup 1.0000x reference)
//
#include <hip/hip_runtime.h>
#include <hip/hip_bf16.h>

typedef __bf16 bf16x8 __attribute__((ext_vector_type(8)));
typedef __bf16 bf16x4 __attribute__((ext_vector_type(4)));
typedef float f32x4 __attribute__((ext_vector_type(4)));

#define KDIM 4096   // K = 128 blocks * 32
#define NDIM 4096   // N = 128 blocks * 32
#define NBJ  128    // output block-columns
#define KB   128    // input  block-rows

#define NB    6        // blocks bulk-staged per batch
#define A_BLK 8192     // 128 rows * 64 B  (bf16 32-k slice for the WG's rows)
#define B_BLK 2048     // 32 rows * 64 B   (one transposed w tile)

// global -> LDS direct copy, 16 B per lane.  Dest must be linear:
// wave-uniform base + lane*16 (m104) — our c = t + k*256 indexing satisfies it.
__device__ __forceinline__ void gload16(const void* g, void* l) {
    __builtin_amdgcn_global_load_lds(
        (const __attribute__((address_space(1))) void*)g,
        (__attribute__((address_space(3))) void*)l, 16, 0, 0);
}

// ---- fused prep: [0, nbCvt) cvt+permute x | [nbCvt, +nnz) wtrans | last: csc
// x-cvt decode is XCD-matched to k_bsmm's rc-major walk (round 9: -8 MB fetch).
__global__ __launch_bounds__(256) void k_prep(
    const float* __restrict__ x, const float* __restrict__ w,
    const int* __restrict__ idx_i, const int* __restrict__ idx_j,
    __bf16* __restrict__ xb, __bf16* __restrict__ wT,
    int* __restrict__ colptr, int* __restrict__ colinfo,
    int nnz, int M, int nbCvt) {
    __shared__ char smem[2176];
    int b = blockIdx.x, t = threadIdx.x;

    if (b < nbCvt) {
        // xb[i][m][k] = bf16(x[m][i*32+k]); 64 rows per WG
        int i, m0;
        if ((M & 1023) == 0) {
            int cpx = M >> 9;             // (M/64)/8 chunks per XCD
            int s = b & 7, r = b >> 3;
            int wch = r >> 7;
            i  = r & (KB - 1);
            m0 = (s * cpx + wch) * 64;
        } else {
            i  = b & (KB - 1);
            m0 = (b >> 7) * 64;
        }
        int q  = t & 3, r = t >> 2;
        const float* xp = x + (size_t)(m0 + r) * KDIM + i * 32 + q * 8;
        float4 u = ((const float4*)xp)[0];
        float4 v = ((const float4*)xp)[1];
        bf16x8 o;
        o[0]=(__bf16)u.x; o[1]=(__bf16)u.y; o[2]=(__bf16)u.z; o[3]=(__bf16)u.w;
        o[4]=(__bf16)v.x; o[5]=(__bf16)v.y; o[6]=(__bf16)v.z; o[7]=(__bf16)v.w;
        *(bf16x8*)(xb + ((size_t)i * M + m0 + r) * 32 + q * 8) = o;
    } else if (b < nbCvt + nnz) {
        // wT[n][c][k] = bf16(w[n][k][c])
        auto tile = (__bf16(*)[33])smem;
        int n = b - nbCvt;
        float4 v = ((const float4*)(w + (size_t)n * 1024))[t];
        int e = t * 4, k = e >> 5, c = e & 31;
        tile[k][c + 0] = (__bf16)v.x; tile[k][c + 1] = (__bf16)v.y;
        tile[k][c + 2] = (__bf16)v.z; tile[k][c + 3] = (__bf16)v.w;
        __syncthreads();
        int f = t * 4, cc = f >> 5, kk = f & 31;
        bf16x4 o;
        o[0] = tile[kk + 0][cc]; o[1] = tile[kk + 1][cc];
        o[2] = tile[kk + 2][cc]; o[3] = tile[kk + 3][cc];
        ((bf16x4*)(wT + (size_t)n * 1024))[t] = o;
    } else {
        // CSC build: colptr + packed (ib<<16)|n colinfo
        int* cnt = (int*)smem;          // [NBJ]
        int* cur = cnt + NBJ;           // [NBJ]
        if (t < NBJ) cnt[t] = 0;
        __syncthreads();
        for (int n = t; n < nnz; n += 256) atomicAdd(&cnt[idx_j[n]], 1);
        __syncthreads();
        int mycount = (t < NBJ) ? cnt[t] : 0;
        for (int off = 1; off < NBJ; off <<= 1) {
            int add = (t < NBJ && t >= off) ? cnt[t - off] : 0;
            __syncthreads();
            if (t < NBJ) cnt[t] += add;
            __syncthreads();
        }
        if (t < NBJ) {
            colptr[t + 1] = cnt[t];
            cur[t] = cnt[t] - mycount;
            if (t == 0) colptr[0] = 0;
        }
        __syncthreads();
        for (int n = t; n < nnz; n += 256) {
            int j = idx_j[n];
            int pos = atomicAdd(&cur[j], 1);
            colinfo[pos] = (idx_i[n] << 16) | n;
        }
    }
}

// ---- main kernel ------------------------------------------------------------
// Bulk-staged batches: per batch each thread issues ~15 global_load_lds
// (A: NB*8 KB, B: NB*2 KB -> ~60 KB/WG in flight) so the kernel runs at the
// memory system's BANDWIDTH equilibrium instead of the 2-outstanding-loads
// latency equilibrium that pinned rounds 0-9 at ~47 us.  A-frags never touch
// VGPRs (rounds 5/7: register-funded depth spills).  Linear LDS layouts
// (gload_lds requirement); all ds_read_b128 patterns are 2 lanes/bank = free.
#define MFMA4(A0, A1, B0, B1)                                                  \
    acc[0][0] = __builtin_amdgcn_mfma_f32_16x16x32_bf16(A0, B0, acc[0][0], 0, 0, 0); \
    acc[0][1] = __builtin_amdgcn_mfma_f32_16x16x32_bf16(A0, B1, acc[0][1], 0, 0, 0); \
    acc[1][0] = __builtin_amdgcn_mfma_f32_16x16x32_bf16(A1, B0, acc[1][0], 0, 0, 0); \
    acc[1][1] = __builtin_amdgcn_mfma_f32_16x16x32_bf16(A1, B1, acc[1][1], 0, 0, 0);

__global__ __launch_bounds__(256) void k_bsmm(
    const __bf16* __restrict__ xb, const __bf16* __restrict__ wT,
    const int* __restrict__ colptr, const int* __restrict__ colinfo,
    float* __restrict__ y, int M) {
    __shared__ int nfo[64];
    __shared__ __attribute__((aligned(16))) char abuf[NB * A_BLK];  // 48 KB
    __shared__ __attribute__((aligned(16))) char bbuf[NB * B_BLK];  // 12 KB

    int RCH = M >> 7;                     // 128-row chunks (4 waves x 32 rows)
    int l = blockIdx.x;
    int rc, j;
    if ((RCH & 7) == 0) {
        // XCD s (= l%8 round-robin) walks all 128 j of one 128-row chunk.
        int rps = RCH >> 3;
        int s = l & 7, u = l >> 3;
        rc = s * rps + (u >> 7);
        j  = u & (NBJ - 1);
    } else {
        rc = l % RCH; j = l / RCH;
    }
    int t = threadIdx.x;
    int lane = t & 63, wave = t >> 6;
    int quad = lane >> 4, l16 = lane & 15;
    int wrow = rc * 128 + wave * 32;

    int beg = colptr[j], end = colptr[j + 1];
    int cnt = end - beg;

    f32x4 acc[2][2] = {};

    size_t strideA = (size_t)M * 32;                       // elems per ib slab
    const __bf16* xslab = xb + (size_t)(rc * 128) * 32;    // + ib*strideA
    const int aoff0 = (wave * 32 + l16) * 64 + quad * 16;  // a0 byte off in A_BLK
    const int boff0 = l16 * 64 + quad * 16;                // b0 byte off in B_BLK

    if (cnt > 0 && cnt <= 64) {
        if (t < cnt) nfo[t] = colinfo[beg + t];
        __syncthreads();

        for (int bb0 = 0; bb0 < cnt; bb0 += NB) {
            int cb = cnt - bb0; if (cb > NB) cb = NB;
            if (bb0 > 0) __syncthreads();              // prior batch fully read

            // bulk issue A: cb * 512 chunks of 16 B (ib uniform per wave)
            for (int c = t; c < cb * 512; c += 256) {
                int b = c >> 9, off = c & 511;
                int ib = nfo[bb0 + b] >> 16;
                gload16(xslab + (size_t)ib * strideA + off * 8,
                        abuf + b * A_BLK + off * 16);
            }
            // bulk issue B: cb * 128 chunks of 16 B (n uniform per wave)
            for (int c = t; c < cb * 128; c += 256) {
                int b = c >> 7, off = c & 127;
                int n = nfo[bb0 + b] & 0xFFFF;
                gload16(wT + (size_t)n * 1024 + off * 8,
                        bbuf + b * B_BLK + off * 16);
            }
            __syncthreads();                           // vmcnt(0) drain + barrier

            for (int p = 0; p < cb; ++p) {
                const char* ap = abuf + p * A_BLK + aoff0;
                const char* bp = bbuf + p * B_BLK + boff0;
                bf16x8 a0 = *(const bf16x8*)(ap);
                bf16x8 a1 = *(const bf16x8*)(ap + 16 * 64);
                bf16x8 b0 = *(const bf16x8*)(bp);
                bf16x8 b1 = *(const bf16x8*)(bp + 16 * 64);
                MFMA4(a0, a1, b0, b1);
            }
        }
    } else if (cnt > 64) {
        // slow path (statistically unreachable at this density)
        for (int bb = beg; bb < end; bb += NB) {
            int cb = end - bb; if (cb > NB) cb = NB;
            if (bb > beg) __syncthreads();
            if (t < cb) nfo[t] = colinfo[bb + t];
            __syncthreads();
            for (int c = t; c < cb * 512; c += 256) {
                int b = c >> 9, off = c & 511;
                int ib = nfo[b] >> 16;
                gload16(xslab + (size_t)ib * strideA + off * 8,
                        abuf + b * A_BLK + off * 16);
            }
            for (int c = t; c < cb * 128; c += 256) {
                int b = c >> 7, off = c & 127;
                int n = nfo[b] & 0xFFFF;
                gload16(wT + (size_t)n * 1024 + off * 8,
                        bbuf + b * B_BLK + off * 16);
            }
            __syncthreads();
            for (int p = 0; p < cb; ++p) {
                const char* ap = abuf + p * A_BLK + aoff0;
                const char* bp = bbuf + p * B_BLK + boff0;
                bf16x8 a0 = *(const bf16x8*)(ap);
                bf16x8 a1 = *(const bf16x8*)(ap + 16 * 64);
                bf16x8 b0 = *(const bf16x8*)(bp);
                bf16x8 b1 = *(const bf16x8*)(bp + 16 * 64);
                MFMA4(a0, a1, b0, b1);
            }
        }
    }

    // C/D layout: row = quad*4 + reg, col = lane&15 (plain stores; NT stores
    // cost +13 MB write amplification in round 9)
    #pragma unroll
    for (int r = 0; r < 2; ++r)
        #pragma unroll
        for (int ch = 0; ch < 2; ++ch)
            #pragma unroll
            for (int reg = 0; reg < 4; ++reg) {
                int row = wrow + r * 16 + quad * 4 + reg;
                int col = j * 32 + ch * 16 + l16;
                y[(size_t)row * NDIM + col] = acc[r][ch][reg];
            }
}

// ---- fallback (no workspace): fp32 reads, convert in-kernel -----------------
__global__ __launch_bounds__(256) void k_bsmm_nows(
    const float* __restrict__ x, const float* __restrict__ w,
    const int* __restrict__ idx_i, const int* __restrict__ idx_j,
    float* __restrict__ y, int nnz) {
    __shared__ int list[256];
    __shared__ int listn;
    __shared__ __bf16 tw[32][40];
    int j = blockIdx.y;
    int tid = threadIdx.x;
    int lane = tid & 63, wave = tid >> 6;
    int quad = lane >> 4, l16 = lane & 15;
    int wrow = blockIdx.x * 256 + wave * 64;

    if (tid == 0) listn = 0;
    __syncthreads();
    for (int n = tid; n < nnz; n += 256)
        if (idx_j[n] == j) { int p = atomicAdd(&listn, 1); list[p & 255] = n; }
    __syncthreads();
    int cnt = listn;

    f32x4 acc[4][2] = {};
    for (int p = 0; p < cnt; ++p) {
        int n = list[p];
        int ib = idx_i[n];
        {
            float4 v = ((const float4*)(w + (size_t)n * 1024))[tid];
            int e = tid * 4, k = e >> 5, c = e & 31;
            tw[c + 0][k] = (__bf16)v.x; tw[c + 1][k] = (__bf16)v.y;
            tw[c + 2][k] = (__bf16)v.z; tw[c + 3][k] = (__bf16)v.w;
        }
        __syncthreads();
        bf16x8 a[4];
        #pragma unroll
        for (int r = 0; r < 4; ++r) {
            const float* xp = x + (size_t)(wrow + r * 16 + l16) * KDIM + ib * 32 + quad * 8;
            float4 u = *(const float4*)(xp);
            float4 v = *(const float4*)(xp + 4);
            a[r][0] = (__bf16)u.x; a[r][1] = (__bf16)u.y; a[r][2] = (__bf16)u.z; a[r][3] = (__bf16)u.w;
            a[r][4] = (__bf16)v.x; a[r][5] = (__bf16)v.y; a[r][6] = (__bf16)v.z; a[r][7] = (__bf16)v.w;
        }
        bf16x8 b0 = *(const bf16x8*)&tw[l16][quad * 8];
        bf16x8 b1 = *(const bf16x8*)&tw[l16 + 16][quad * 8];
        #pragma unroll
        for (int r = 0; r < 4; ++r) {
            acc[r][0] = __builtin_amdgcn_mfma_f32_16x16x32_bf16(a[r], b0, acc[r][0], 0, 0, 0);
            acc[r][1] = __builtin_amdgcn_mfma_f32_16x16x32_bf16(a[r], b1, acc[r][1], 0, 0, 0);
        }
        __syncthreads();
    }

    #pragma unroll
    for (int r = 0; r < 4; ++r)
        #pragma unroll
        for (int ch = 0; ch < 2; ++ch)
            #pragma unroll
            for (int reg = 0; reg < 4; ++reg) {
                int row = wrow + r * 16 + quad * 4 + reg;
                int col = j * 32 + ch * 16 + l16;
                y[(size_t)row * NDIM + col] = acc[r][ch][reg];
            }
}

extern "C" void kernel_launch(void* const* d_in, const int* in_sizes, int n_in,
                              void* d_out, int out_size, void* d_ws, size_t ws_size,
                              hipStream_t stream) {
    const float* x     = (const float*)d_in[0];
    const float* w     = (const float*)d_in[1];
    const int*   idx_i = (const int*)d_in[2];
    const int*   idx_j = (const int*)d_in[3];
    float*       y     = (float*)d_out;

    int nnz = in_sizes[2];
    int M   = in_sizes[0] / KDIM;                   // 4096

    size_t xb_bytes = (size_t)M * KDIM * 2;         // 32 MB
    size_t wt_bytes = (size_t)nnz * 1024 * 2;
    size_t need = xb_bytes + wt_bytes + (size_t)(NBJ + 2 + nnz) * 4;

    if (ws_size >= need && (M & 255) == 0 && nnz < 65536) {
        __bf16* xb      = (__bf16*)d_ws;
        __bf16* wT      = (__bf16*)((char*)d_ws + xb_bytes);
        int*    colptr  = (int*)((char*)d_ws + xb_bytes + wt_bytes);
        int*    colinfo = colptr + NBJ + 1;
        int nbCvt = KB * (M / 64);                  // 8192
        k_prep<<<nbCvt + nnz + 1, 256, 0, stream>>>(x, w, idx_i, idx_j,
                                                    xb, wT, colptr, colinfo,
                                                    nnz, M, nbCvt);
        k_bsmm<<<(M / 128) * NBJ, 256, 0, stream>>>(xb, wT, colptr, colinfo, y, M);
    } else {
        k_bsmm_nows<<<dim3(M / 256, NBJ), 256, 0, stream>>>(x, w, idx_i, idx_j, y, nnz);
    }
}